// Round 8
// baseline (125.567 us; speedup 1.0000x reference)
//
#include <hip/hip_runtime.h>

// B=32, N=128, Fin=Fout=64, K_HOPS=4
// ws layout (BYTE offsets), total 5 MB:
//   The @ 0MB   : bf16-hi of T', [f][m][k]  64*128*64*2 = 1 MB
//   Tle @ 1MB   : bf16-lo                               = 1 MB
//   OQh @ 2MB   : bf16-hi of (Px+Bb)Q, [b][n][k] 32*128*64*2 = 512 KB
//   OQl @ 2.5MB : bf16-lo                                     = 512 KB
//   Xft @ 3MB   : f32 [b][f][n]  32*64*128*4                  = 1 MB
//   xT  @ 4MB   : f32 [b][f][n]  32*64*128*4                  = 1 MB

typedef __attribute__((ext_vector_type(8))) short short8v;
typedef __attribute__((ext_vector_type(4))) float f32x4;

#define WS_THE 0u
#define WS_TLE (1u << 20)
#define WS_OQH (2u << 20)
#define WS_OQL ((2u << 20) + (512u << 10))
#define WS_XFT (3u << 20)
#define WS_XT  (4u << 20)

__device__ __forceinline__ void split_bf16(float a, unsigned& hi, unsigned& lo) {
  unsigned ha = __float_as_uint(a) & 0xffff0000u;
  float d = a - __uint_as_float(ha);          // exact residual
  unsigned la = __float_as_uint(d) & 0xffff0000u;
  hi = ha; lo = la;                           // bf16 bits in TOP 16
}

// kpre: blocks 0..63   -> T[k][m*64+f] -> The/Tle[f][m][k] (transpose + split)
//       blocks 64..191 -> O = P x + Bb; OQh/OQl[b][n][k] = split((O Q)[n][k])
//       blocks 192..255-> x[b][n][f] -> xT[b][f][n] (LDS-tiled transpose)
__global__ __launch_bounds__(256) void iag_kpre(
    const float* __restrict__ T, const float* __restrict__ x,
    const float* __restrict__ P, const float* __restrict__ Q,
    const float* __restrict__ Bb,
    unsigned short* __restrict__ The, unsigned short* __restrict__ Tle,
    unsigned short* __restrict__ OQh, unsigned short* __restrict__ OQl,
    float* __restrict__ xT) {
  __shared__ __align__(16) char smem[73856];
  int bi = blockIdx.x, tid = threadIdx.x;

  if (bi < 64) {  // ---- T split-transpose: m-chunk of 2, all k, all f ----
    float* tile = (float*)smem;               // [64][129] f32
    int m0 = bi * 2;
    for (int idx = tid; idx < 8192; idx += 256) {
      int k = idx >> 7, j = idx & 127;        // j = ml*64 + f, coalesced read
      tile[k * 129 + j] = T[k * 8192 + m0 * 64 + j];
    }
    __syncthreads();
    int p = tid >> 1, kc = (tid & 1) * 32;
    int fj = p & 63, ml = p >> 6;
    int j = ml * 64 + fj;                     // bank (kk+j)%32: 2-way max
    unsigned hw[16], lw[16];
#pragma unroll
    for (int kk = 0; kk < 32; kk += 2) {
      float a0 = tile[(kc + kk) * 129 + j];
      float a1 = tile[(kc + kk + 1) * 129 + j];
      unsigned h0, l0, h1, l1;
      split_bf16(a0, h0, l0);
      split_bf16(a1, h1, l1);
      hw[kk >> 1] = (h0 >> 16) | h1;
      lw[kk >> 1] = (l0 >> 16) | l1;
    }
    uint4* dh = (uint4*)(The + fj * 8192 + (m0 + ml) * 64 + kc);
    uint4* dl = (uint4*)(Tle + fj * 8192 + (m0 + ml) * 64 + kc);
#pragma unroll
    for (int i = 0; i < 4; ++i) {
      dh[i] = make_uint4(hw[4 * i], hw[4 * i + 1], hw[4 * i + 2], hw[4 * i + 3]);
      dl[i] = make_uint4(lw[4 * i], lw[4 * i + 1], lw[4 * i + 2], lw[4 * i + 3]);
    }
  } else if (bi < 192) {  // ---- OQ compute + split ----
    float* x_s   = (float*)smem;              // [128][64]
    float* ptile = x_s + 128 * 64;            // [32][129]
    float* Q_s   = ptile + 32 * 129;          // [64][64]
    float* OcT   = Q_s + 64 * 64;             // [64][32]
    int jb = bi - 64;
    int b = jb >> 2, r0 = (jb & 3) * 32;

    const float4* xg = (const float4*)(x + b * 8192);
    float4* xs4 = (float4*)x_s;
    for (int idx = tid; idx < 2048; idx += 256) xs4[idx] = xg[idx];
    for (int idx = tid; idx < 4096; idx += 256) {
      int nl = idx >> 7, m = idx & 127;
      ptile[nl * 129 + m] = P[(r0 + nl) * 128 + m];
    }
    const float4* qg = (const float4*)Q;
    float4* qs4 = (float4*)Q_s;
    for (int idx = tid; idx < 1024; idx += 256) qs4[idx] = qg[idx];
    __syncthreads();

    {  // Stage A: O[nl][k0..k0+7]
      int nl = tid & 31, k0 = (tid >> 5) * 8;
      float bias = Bb[r0 + nl];
      float a[8];
#pragma unroll
      for (int j = 0; j < 8; ++j) a[j] = bias;
#pragma unroll 4
      for (int m = 0; m < 128; ++m) {
        float p = ptile[nl * 129 + m];
        float4 x0 = xs4[m * 16 + (k0 >> 2)];
        float4 x1 = xs4[m * 16 + (k0 >> 2) + 1];
        a[0] += p * x0.x; a[1] += p * x0.y; a[2] += p * x0.z; a[3] += p * x0.w;
        a[4] += p * x1.x; a[5] += p * x1.y; a[6] += p * x1.z; a[7] += p * x1.w;
      }
#pragma unroll
      for (int j = 0; j < 8; ++j) OcT[(k0 + j) * 32 + nl] = a[j];
    }
    __syncthreads();
    {  // Stage B: row n = r0 + (tid>>3), cols j0..j0+7 of OQ; split+store
      int nl = tid >> 3, j0 = (tid & 7) * 8;
      float c[8];
#pragma unroll
      for (int i = 0; i < 8; ++i) c[i] = 0.f;
      const float4* q4 = (const float4*)Q_s;
#pragma unroll 4
      for (int k = 0; k < 64; ++k) {
        float o = OcT[k * 32 + nl];
        float4 q0 = q4[k * 16 + (j0 >> 2)];
        float4 q1 = q4[k * 16 + (j0 >> 2) + 1];
        c[0] += o * q0.x; c[1] += o * q0.y; c[2] += o * q0.z; c[3] += o * q0.w;
        c[4] += o * q1.x; c[5] += o * q1.y; c[6] += o * q1.z; c[7] += o * q1.w;
      }
      unsigned hw[4], lw[4];
#pragma unroll
      for (int j = 0; j < 8; j += 2) {
        unsigned h0, l0, h1, l1;
        split_bf16(c[j], h0, l0);
        split_bf16(c[j + 1], h1, l1);
        hw[j >> 1] = (h0 >> 16) | h1;
        lw[j >> 1] = (l0 >> 16) | l1;
      }
      int n = r0 + nl;
      *(uint4*)(OQh + b * 8192 + n * 64 + j0) = make_uint4(hw[0], hw[1], hw[2], hw[3]);
      *(uint4*)(OQl + b * 8192 + n * 64 + j0) = make_uint4(lw[0], lw[1], lw[2], lw[3]);
    }
  } else {  // ---- x -> xT LDS-tiled transpose ----
    float* tile = (float*)smem;               // [64][65] f32
    int j = bi - 192;
    int b = j >> 1, half = j & 1;
    const float* src = x + b * 8192 + half * 4096;
    float* dstbase = xT + b * 8192 + half * 64;
    for (int idx = tid; idx < 4096; idx += 256) {
      int c = idx & 63, r = idx >> 6;         // c = f (minor, coalesced read)
      tile[r * 65 + c] = src[idx];
    }
    __syncthreads();
    for (int idx = tid; idx < 4096; idx += 256) {
      int r = idx & 63, c = idx >> 6;         // r minor -> coalesced write
      dstbase[c * 128 + r] = tile[r * 65 + c];
    }
  }
}

// k2: per (f, b): G = OQ^T x Tf via split-bf16 MFMA (hh + hl + lh), relu,
// degree-normalize (ref quirk: colsum applied at n, rowsum at m), 3 hops.
// Operands direct from global (L2-resident); B ping-pong prefetched.
// launch_bounds (256,3): 170-reg cap fits acc(64)+frags(32)+B(32)+addr — no spill.
__global__ __launch_bounds__(256, 3) void iag_k2_graph(
    const unsigned short* __restrict__ OQh, const unsigned short* __restrict__ OQl,
    const unsigned short* __restrict__ The, const unsigned short* __restrict__ Tle,
    const float* __restrict__ xT, float* __restrict__ Xft) {
  __shared__ float red[4 * 128];
  __shared__ float invc[128], invr[128];
  __shared__ float wvb[2][128];
  int f = blockIdx.x, b = blockIdx.y, tid = threadIdx.x;

  if (tid < 128) wvb[0][tid] = xT[(b * 64 + f) * 128 + tid];  // contiguous

  int lane = tid & 63, w = tid >> 6;
  int li = lane & 15, lk = lane >> 4;

  const unsigned short* Abh = OQh + b * 8192;
  const unsigned short* Abl = OQl + b * 8192;
  const unsigned short* Bbh = The + f * 8192;
  const unsigned short* Bbl = Tle + f * 8192;

  // A-frags: wave w owns rows n in [32w, 32w+32)
  short8v ah[2][2], al[2][2];
#pragma unroll
  for (int nt = 0; nt < 2; ++nt)
#pragma unroll
    for (int kh = 0; kh < 2; ++kh) {
      int off = (w * 32 + nt * 16 + li) * 64 + kh * 32 + lk * 8;
      ah[nt][kh] = *(const short8v*)(Abh + off);
      al[nt][kh] = *(const short8v*)(Abl + off);
    }

  f32x4 acc[2][8];
#pragma unroll
  for (int nt = 0; nt < 2; ++nt)
#pragma unroll
    for (int mt = 0; mt < 8; ++mt) acc[nt][mt] = (f32x4){0.f, 0.f, 0.f, 0.f};

  // B ping-pong: slot indices compile-time after full unroll (no scratch)
  short8v pb[2][4];
  {
    int off0 = li * 64 + lk * 8;
    pb[0][0] = *(const short8v*)(Bbh + off0);
    pb[0][1] = *(const short8v*)(Bbh + off0 + 32);
    pb[0][2] = *(const short8v*)(Bbl + off0);
    pb[0][3] = *(const short8v*)(Bbl + off0 + 32);
  }
#pragma unroll
  for (int mt = 0; mt < 8; ++mt) {
    int slot = mt & 1;
    if (mt < 7) {
      int off = ((mt + 1) * 16 + li) * 64 + lk * 8;
      pb[slot ^ 1][0] = *(const short8v*)(Bbh + off);
      pb[slot ^ 1][1] = *(const short8v*)(Bbh + off + 32);
      pb[slot ^ 1][2] = *(const short8v*)(Bbl + off);
      pb[slot ^ 1][3] = *(const short8v*)(Bbl + off + 32);
    }
#pragma unroll
    for (int nt = 0; nt < 2; ++nt) {
      f32x4 a = acc[nt][mt];
      a = __builtin_amdgcn_mfma_f32_16x16x32_bf16(ah[nt][0], pb[slot][0], a, 0, 0, 0);
      a = __builtin_amdgcn_mfma_f32_16x16x32_bf16(ah[nt][1], pb[slot][1], a, 0, 0, 0);
      a = __builtin_amdgcn_mfma_f32_16x16x32_bf16(ah[nt][0], pb[slot][2], a, 0, 0, 0);
      a = __builtin_amdgcn_mfma_f32_16x16x32_bf16(ah[nt][1], pb[slot][3], a, 0, 0, 0);
      a = __builtin_amdgcn_mfma_f32_16x16x32_bf16(al[nt][0], pb[slot][0], a, 0, 0, 0);
      a = __builtin_amdgcn_mfma_f32_16x16x32_bf16(al[nt][1], pb[slot][1], a, 0, 0, 0);
      acc[nt][mt] = a;
    }
  }

  // relu. Lane holds D[n][m]: n = 32w + nt*16 + lk*4 + r, m = mt*16 + li.
#pragma unroll
  for (int nt = 0; nt < 2; ++nt)
#pragma unroll
    for (int mt = 0; mt < 8; ++mt)
#pragma unroll
      for (int r = 0; r < 4; ++r) acc[nt][mt][r] = fmaxf(acc[nt][mt][r], 0.f);

  // colsum c[m] = sum_n G[n][m] (cross-wave via red)
#pragma unroll
  for (int mt = 0; mt < 8; ++mt) {
    float cs = 0.f;
#pragma unroll
    for (int nt = 0; nt < 2; ++nt)
#pragma unroll
      for (int r = 0; r < 4; ++r) cs += acc[nt][mt][r];
    cs += __shfl_xor(cs, 16);
    cs += __shfl_xor(cs, 32);
    if (lk == 0) red[w * 128 + mt * 16 + li] = cs;
  }
  // rowsum r[n] = sum_m G[n][m] (intra-wave butterfly over li)
  {
    float rs[2][4];
#pragma unroll
    for (int nt = 0; nt < 2; ++nt)
#pragma unroll
      for (int r = 0; r < 4; ++r) {
        float s = 0.f;
#pragma unroll
        for (int mt = 0; mt < 8; ++mt) s += acc[nt][mt][r];
        rs[nt][r] = s;
      }
#pragma unroll
    for (int d = 1; d <= 8; d <<= 1)
#pragma unroll
      for (int nt = 0; nt < 2; ++nt)
#pragma unroll
        for (int r = 0; r < 4; ++r) rs[nt][r] += __shfl_xor(rs[nt][r], d);
    if (li == 0) {
#pragma unroll
      for (int nt = 0; nt < 2; ++nt)
#pragma unroll
        for (int r = 0; r < 4; ++r)
          invr[w * 32 + nt * 16 + lk * 4 + r] = rs[nt][r];  // raw rowsum
    }
  }
  __syncthreads();
  if (tid < 128) {
    float csum = red[tid] + red[128 + tid] + red[256 + tid] + red[384 + tid];
    invc[tid] = 1.0f / sqrtf(csum);
    invr[tid] = 1.0f / sqrtf(invr[tid]);
  }
  __syncthreads();

  // normalize: A[n][m] = G * invc[n] * invr[m]  (ref quirk preserved)
  {
    float icf[2][4], irf[8];
#pragma unroll
    for (int nt = 0; nt < 2; ++nt)
#pragma unroll
      for (int r = 0; r < 4; ++r) icf[nt][r] = invc[w * 32 + nt * 16 + lk * 4 + r];
#pragma unroll
    for (int mt = 0; mt < 8; ++mt) irf[mt] = invr[mt * 16 + li];
#pragma unroll
    for (int nt = 0; nt < 2; ++nt)
#pragma unroll
      for (int mt = 0; mt < 8; ++mt)
#pragma unroll
        for (int r = 0; r < 4; ++r) acc[nt][mt][r] *= icf[nt][r] * irf[mt];
  }

  // s = x; 3 hops: w' = A w, s += w'
  float sv[2][4];
#pragma unroll
  for (int nt = 0; nt < 2; ++nt)
#pragma unroll
    for (int r = 0; r < 4; ++r) sv[nt][r] = wvb[0][w * 32 + nt * 16 + lk * 4 + r];
  int cur = 0;
  for (int h = 0; h < 3; ++h) {
    float wr[8];
#pragma unroll
    for (int mt = 0; mt < 8; ++mt) wr[mt] = wvb[cur][mt * 16 + li];
    float p[2][4];
#pragma unroll
    for (int nt = 0; nt < 2; ++nt)
#pragma unroll
      for (int r = 0; r < 4; ++r) {
        float s = 0.f;
#pragma unroll
        for (int mt = 0; mt < 8; ++mt) s += acc[nt][mt][r] * wr[mt];
        p[nt][r] = s;
      }
#pragma unroll
    for (int d = 1; d <= 8; d <<= 1)
#pragma unroll
      for (int nt = 0; nt < 2; ++nt)
#pragma unroll
        for (int r = 0; r < 4; ++r) p[nt][r] += __shfl_xor(p[nt][r], d);
#pragma unroll
    for (int nt = 0; nt < 2; ++nt)
#pragma unroll
      for (int r = 0; r < 4; ++r) sv[nt][r] += p[nt][r];
    if (li == 0) {
#pragma unroll
      for (int nt = 0; nt < 2; ++nt)
#pragma unroll
        for (int r = 0; r < 4; ++r)
          wvb[cur ^ 1][w * 32 + nt * 16 + lk * 4 + r] = p[nt][r];
    }
    __syncthreads();
    cur ^= 1;
  }
  if (li == 0) {
#pragma unroll
    for (int nt = 0; nt < 2; ++nt)
#pragma unroll
      for (int r = 0; r < 4; ++r)
        Xft[(b * 64 + f) * 128 + w * 32 + nt * 16 + lk * 4 + r] = sv[nt][r];
  }
}

// k3: out[b][n][j] = sum_f Xft[b][f][n] * U[f][j]; grid (4 n-chunks, 32 b)
__global__ __launch_bounds__(256) void iag_k3_out(
    const float* __restrict__ Xft, const float* __restrict__ U,
    float* __restrict__ out) {
  __shared__ float Xf_s[64 * 36];                 // [f][nl], 144B rows
  __shared__ __align__(16) float U_s[64 * 64];
  int b = blockIdx.y, n0 = blockIdx.x * 32, tid = threadIdx.x;
  for (int c = tid; c < 512; c += 256) {
    int ff = c >> 3, s = c & 7;
    float4 v = *(const float4*)(Xft + (b * 64 + ff) * 128 + n0 + s * 4);
    *(float4*)(Xf_s + ff * 36 + s * 4) = v;
  }
  const float4* ug = (const float4*)U;
  float4* us = (float4*)U_s;
  for (int c = tid; c < 1024; c += 256) us[c] = ug[c];
  __syncthreads();

  int j0 = (tid & 15) * 4, nl0 = (tid >> 4) * 2;
  float a0[4] = {0.f, 0.f, 0.f, 0.f}, a1[4] = {0.f, 0.f, 0.f, 0.f};
  const float4* u4 = (const float4*)U_s;
#pragma unroll 4
  for (int ff = 0; ff < 64; ++ff) {
    float4 u = u4[ff * 16 + (j0 >> 2)];
    float xa = Xf_s[ff * 36 + nl0];
    float xb = Xf_s[ff * 36 + nl0 + 1];
    a0[0] += xa * u.x; a0[1] += xa * u.y; a0[2] += xa * u.z; a0[3] += xa * u.w;
    a1[0] += xb * u.x; a1[1] += xb * u.y; a1[2] += xb * u.z; a1[3] += xb * u.w;
  }
  *(float4*)(out + b * 8192 + (n0 + nl0) * 64 + j0) =
      make_float4(a0[0], a0[1], a0[2], a0[3]);
  *(float4*)(out + b * 8192 + (n0 + nl0 + 1) * 64 + j0) =
      make_float4(a1[0], a1[1], a1[2], a1[3]);
}

extern "C" void kernel_launch(void* const* d_in, const int* in_sizes, int n_in,
                              void* d_out, int out_size, void* d_ws, size_t ws_size,
                              hipStream_t stream) {
  const float* x  = (const float*)d_in[0];
  const float* P  = (const float*)d_in[1];
  const float* Bb = (const float*)d_in[2];
  const float* Q  = (const float*)d_in[3];
  const float* T  = (const float*)d_in[4];
  const float* U  = (const float*)d_in[5];
  char* wsb = (char*)d_ws;
  unsigned short* The = (unsigned short*)(wsb + WS_THE);
  unsigned short* Tle = (unsigned short*)(wsb + WS_TLE);
  unsigned short* OQh = (unsigned short*)(wsb + WS_OQH);
  unsigned short* OQl = (unsigned short*)(wsb + WS_OQL);
  float* Xft = (float*)(wsb + WS_XFT);
  float* xT  = (float*)(wsb + WS_XT);

  iag_kpre<<<256, 256, 0, stream>>>(T, x, P, Q, Bb, The, Tle, OQh, OQl, xT);
  iag_k2_graph<<<dim3(64, 32), 256, 0, stream>>>(OQh, OQl, The, Tle, xT, Xft);
  iag_k3_out<<<dim3(4, 32), 256, 0, stream>>>(Xft, U, (float*)d_out);
}

// Round 9
// 109.793 us; speedup vs baseline: 1.1437x; 1.1437x over previous
//
#include <hip/hip_runtime.h>

// B=32, N=128, Fin=Fout=64, K_HOPS=4
// ws layout (BYTE offsets), total 5 MB:
//   The @ 0MB   : bf16-hi of T', [f][m][k]  64*128*64*2 = 1 MB
//   Tle @ 1MB   : bf16-lo                               = 1 MB
//   OQh @ 2MB   : bf16-hi of (Px+Bb)Q, [b][n][k] 32*128*64*2 = 512 KB
//   OQl @ 2.5MB : bf16-lo                                     = 512 KB
//   Xft @ 3MB   : f32 [b][f][n]  32*64*128*4                  = 1 MB
//   xT  @ 4MB   : f32 [b][f][n]  32*64*128*4                  = 1 MB

typedef __attribute__((ext_vector_type(8))) short short8v;
typedef __attribute__((ext_vector_type(4))) float f32x4;

#define WS_THE 0u
#define WS_TLE (1u << 20)
#define WS_OQH (2u << 20)
#define WS_OQL ((2u << 20) + (512u << 10))
#define WS_XFT (3u << 20)
#define WS_XT  (4u << 20)

__device__ __forceinline__ void split_bf16(float a, unsigned& hi, unsigned& lo) {
  unsigned ha = __float_as_uint(a) & 0xffff0000u;
  float d = a - __uint_as_float(ha);          // exact residual
  unsigned la = __float_as_uint(d) & 0xffff0000u;
  hi = ha; lo = la;                           // bf16 bits in TOP 16
}

// kpre: blocks 0..63   -> T[k][m*64+f] -> The/Tle[f][m][k] (transpose + split)
//       blocks 64..191 -> O = P x + Bb; OQh/OQl[b][n][k] = split((O Q)[n][k])
//       blocks 192..255-> x[b][n][f] -> xT[b][f][n] (LDS-tiled transpose)
__global__ __launch_bounds__(256) void iag_kpre(
    const float* __restrict__ T, const float* __restrict__ x,
    const float* __restrict__ P, const float* __restrict__ Q,
    const float* __restrict__ Bb,
    unsigned short* __restrict__ The, unsigned short* __restrict__ Tle,
    unsigned short* __restrict__ OQh, unsigned short* __restrict__ OQl,
    float* __restrict__ xT) {
  __shared__ __align__(16) char smem[73856];
  int bi = blockIdx.x, tid = threadIdx.x;

  if (bi < 64) {  // ---- T split-transpose: m-chunk of 2, all k, all f ----
    float* tile = (float*)smem;               // [64][129] f32
    int m0 = bi * 2;
    for (int idx = tid; idx < 8192; idx += 256) {
      int k = idx >> 7, j = idx & 127;        // j = ml*64 + f, coalesced read
      tile[k * 129 + j] = T[k * 8192 + m0 * 64 + j];
    }
    __syncthreads();
    int p = tid >> 1, kc = (tid & 1) * 32;
    int fj = p & 63, ml = p >> 6;
    int j = ml * 64 + fj;                     // bank (kk+j)%32: 2-way max
    unsigned hw[16], lw[16];
#pragma unroll
    for (int kk = 0; kk < 32; kk += 2) {
      float a0 = tile[(kc + kk) * 129 + j];
      float a1 = tile[(kc + kk + 1) * 129 + j];
      unsigned h0, l0, h1, l1;
      split_bf16(a0, h0, l0);
      split_bf16(a1, h1, l1);
      hw[kk >> 1] = (h0 >> 16) | h1;
      lw[kk >> 1] = (l0 >> 16) | l1;
    }
    uint4* dh = (uint4*)(The + fj * 8192 + (m0 + ml) * 64 + kc);
    uint4* dl = (uint4*)(Tle + fj * 8192 + (m0 + ml) * 64 + kc);
#pragma unroll
    for (int i = 0; i < 4; ++i) {
      dh[i] = make_uint4(hw[4 * i], hw[4 * i + 1], hw[4 * i + 2], hw[4 * i + 3]);
      dl[i] = make_uint4(lw[4 * i], lw[4 * i + 1], lw[4 * i + 2], lw[4 * i + 3]);
    }
  } else if (bi < 192) {  // ---- OQ compute + split ----
    float* x_s   = (float*)smem;              // [128][64]
    float* ptile = x_s + 128 * 64;            // [32][129]
    float* Q_s   = ptile + 32 * 129;          // [64][64]
    float* OcT   = Q_s + 64 * 64;             // [64][32]
    int jb = bi - 64;
    int b = jb >> 2, r0 = (jb & 3) * 32;

    const float4* xg = (const float4*)(x + b * 8192);
    float4* xs4 = (float4*)x_s;
    for (int idx = tid; idx < 2048; idx += 256) xs4[idx] = xg[idx];
    for (int idx = tid; idx < 4096; idx += 256) {
      int nl = idx >> 7, m = idx & 127;
      ptile[nl * 129 + m] = P[(r0 + nl) * 128 + m];
    }
    const float4* qg = (const float4*)Q;
    float4* qs4 = (float4*)Q_s;
    for (int idx = tid; idx < 1024; idx += 256) qs4[idx] = qg[idx];
    __syncthreads();

    {  // Stage A: O[nl][k0..k0+7]
      int nl = tid & 31, k0 = (tid >> 5) * 8;
      float bias = Bb[r0 + nl];
      float a[8];
#pragma unroll
      for (int j = 0; j < 8; ++j) a[j] = bias;
#pragma unroll 4
      for (int m = 0; m < 128; ++m) {
        float p = ptile[nl * 129 + m];
        float4 x0 = xs4[m * 16 + (k0 >> 2)];
        float4 x1 = xs4[m * 16 + (k0 >> 2) + 1];
        a[0] += p * x0.x; a[1] += p * x0.y; a[2] += p * x0.z; a[3] += p * x0.w;
        a[4] += p * x1.x; a[5] += p * x1.y; a[6] += p * x1.z; a[7] += p * x1.w;
      }
#pragma unroll
      for (int j = 0; j < 8; ++j) OcT[(k0 + j) * 32 + nl] = a[j];
    }
    __syncthreads();
    {  // Stage B: row n = r0 + (tid>>3), cols j0..j0+7 of OQ; split+store
      int nl = tid >> 3, j0 = (tid & 7) * 8;
      float c[8];
#pragma unroll
      for (int i = 0; i < 8; ++i) c[i] = 0.f;
      const float4* q4 = (const float4*)Q_s;
#pragma unroll 4
      for (int k = 0; k < 64; ++k) {
        float o = OcT[k * 32 + nl];
        float4 q0 = q4[k * 16 + (j0 >> 2)];
        float4 q1 = q4[k * 16 + (j0 >> 2) + 1];
        c[0] += o * q0.x; c[1] += o * q0.y; c[2] += o * q0.z; c[3] += o * q0.w;
        c[4] += o * q1.x; c[5] += o * q1.y; c[6] += o * q1.z; c[7] += o * q1.w;
      }
      unsigned hw[4], lw[4];
#pragma unroll
      for (int j = 0; j < 8; j += 2) {
        unsigned h0, l0, h1, l1;
        split_bf16(c[j], h0, l0);
        split_bf16(c[j + 1], h1, l1);
        hw[j >> 1] = (h0 >> 16) | h1;
        lw[j >> 1] = (l0 >> 16) | l1;
      }
      int n = r0 + nl;
      *(uint4*)(OQh + b * 8192 + n * 64 + j0) = make_uint4(hw[0], hw[1], hw[2], hw[3]);
      *(uint4*)(OQl + b * 8192 + n * 64 + j0) = make_uint4(lw[0], lw[1], lw[2], lw[3]);
    }
  } else {  // ---- x -> xT LDS-tiled transpose ----
    float* tile = (float*)smem;               // [64][65] f32
    int j = bi - 192;
    int b = j >> 1, half = j & 1;
    const float* src = x + b * 8192 + half * 4096;
    float* dstbase = xT + b * 8192 + half * 64;
    for (int idx = tid; idx < 4096; idx += 256) {
      int c = idx & 63, r = idx >> 6;         // c = f (minor, coalesced read)
      tile[r * 65 + c] = src[idx];
    }
    __syncthreads();
    for (int idx = tid; idx < 4096; idx += 256) {
      int r = idx & 63, c = idx >> 6;         // r minor -> coalesced write
      dstbase[c * 128 + r] = tile[r * 65 + c];
    }
  }
}

// k2: persistent 768 blocks grid-striding 2048 (f,b) tiles.
// Per tile: G = OQ^T x Tf via split-bf16 MFMA (hh+hl+lh), relu, degree-
// normalize (ref quirk: colsum applied at n, rowsum at m), 3 matvec hops.
// B-planes staged in LDS, FRAGMENT-MAJOR Bs[kh][mt][li][lk][8]: each wave's
// ds_read_b128 covers a contiguous 1KB block -> conflict-free. A direct-global.
__global__ __launch_bounds__(256, 3) void iag_k2_graph(
    const unsigned short* __restrict__ OQh, const unsigned short* __restrict__ OQl,
    const unsigned short* __restrict__ The, const unsigned short* __restrict__ Tle,
    const float* __restrict__ xT, float* __restrict__ Xft) {
  __shared__ unsigned short Bh_s[8192], Bl_s[8192];   // 16KB each, frag-major
  __shared__ float red[4 * 128];
  __shared__ float invc[128], invr[128];
  __shared__ float wvb[2][128];
  int tid = threadIdx.x;
  int lane = tid & 63, w = tid >> 6;
  int li = lane & 15, lk = lane >> 4;

  for (int t = blockIdx.x; t < 2048; t += 768) {
    int f = t & 63, b = t >> 6;

    if (tid < 128) wvb[0][tid] = xT[(b * 64 + f) * 128 + tid];

    // A-frags issued first so they fly under the B-stage
    const unsigned short* Abh = OQh + b * 8192;
    const unsigned short* Abl = OQl + b * 8192;
    short8v ah[2][2], al[2][2];
#pragma unroll
    for (int nt = 0; nt < 2; ++nt)
#pragma unroll
      for (int kh = 0; kh < 2; ++kh) {
        int off = (w * 32 + nt * 16 + li) * 64 + kh * 32 + lk * 8;
        ah[nt][kh] = *(const short8v*)(Abh + off);
        al[nt][kh] = *(const short8v*)(Abl + off);
      }

    // stage B: global chunk c (coalesced 16B) -> frag-major LDS slot
    {
      const unsigned short* Bbh = The + f * 8192;
      const unsigned short* Bbl = Tle + f * 8192;
#pragma unroll
      for (int it = 0; it < 4; ++it) {
        int c = tid + it * 256;               // c = row*8 + kh*4 + lkc
        int row = c >> 3, kh = (c >> 2) & 1, lkc = c & 3;
        int dst = kh * 4096 + (row >> 4) * 512 + (row & 15) * 32 + lkc * 8;
        *(uint4*)(Bh_s + dst) = *(const uint4*)(Bbh + c * 8);
        *(uint4*)(Bl_s + dst) = *(const uint4*)(Bbl + c * 8);
      }
    }
    __syncthreads();

    f32x4 acc[2][8];
#pragma unroll
    for (int nt = 0; nt < 2; ++nt)
#pragma unroll
      for (int mt = 0; mt < 8; ++mt) acc[nt][mt] = (f32x4){0.f, 0.f, 0.f, 0.f};

#pragma unroll
    for (int mt = 0; mt < 8; ++mt) {
      int base = mt * 512 + li * 32 + lk * 8;  // lane-contiguous within wave
      short8v bh0 = *(const short8v*)(Bh_s + base);
      short8v bh1 = *(const short8v*)(Bh_s + 4096 + base);
      short8v bl0 = *(const short8v*)(Bl_s + base);
      short8v bl1 = *(const short8v*)(Bl_s + 4096 + base);
#pragma unroll
      for (int nt = 0; nt < 2; ++nt) {
        f32x4 a = acc[nt][mt];
        a = __builtin_amdgcn_mfma_f32_16x16x32_bf16(ah[nt][0], bh0, a, 0, 0, 0);
        a = __builtin_amdgcn_mfma_f32_16x16x32_bf16(ah[nt][1], bh1, a, 0, 0, 0);
        a = __builtin_amdgcn_mfma_f32_16x16x32_bf16(ah[nt][0], bl0, a, 0, 0, 0);
        a = __builtin_amdgcn_mfma_f32_16x16x32_bf16(ah[nt][1], bl1, a, 0, 0, 0);
        a = __builtin_amdgcn_mfma_f32_16x16x32_bf16(al[nt][0], bh0, a, 0, 0, 0);
        a = __builtin_amdgcn_mfma_f32_16x16x32_bf16(al[nt][1], bh1, a, 0, 0, 0);
        acc[nt][mt] = a;
      }
    }

    // relu. Lane holds D[n][m]: n = 32w + nt*16 + lk*4 + r, m = mt*16 + li.
#pragma unroll
    for (int nt = 0; nt < 2; ++nt)
#pragma unroll
      for (int mt = 0; mt < 8; ++mt)
#pragma unroll
        for (int r = 0; r < 4; ++r) acc[nt][mt][r] = fmaxf(acc[nt][mt][r], 0.f);

    // colsum c[m] = sum_n G[n][m] (cross-wave via red)
#pragma unroll
    for (int mt = 0; mt < 8; ++mt) {
      float cs = 0.f;
#pragma unroll
      for (int nt = 0; nt < 2; ++nt)
#pragma unroll
        for (int r = 0; r < 4; ++r) cs += acc[nt][mt][r];
      cs += __shfl_xor(cs, 16);
      cs += __shfl_xor(cs, 32);
      if (lk == 0) red[w * 128 + mt * 16 + li] = cs;
    }
    // rowsum r[n] = sum_m G[n][m] (intra-wave butterfly over li)
    {
      float rs[2][4];
#pragma unroll
      for (int nt = 0; nt < 2; ++nt)
#pragma unroll
        for (int r = 0; r < 4; ++r) {
          float s = 0.f;
#pragma unroll
          for (int mt = 0; mt < 8; ++mt) s += acc[nt][mt][r];
          rs[nt][r] = s;
        }
#pragma unroll
      for (int d = 1; d <= 8; d <<= 1)
#pragma unroll
        for (int nt = 0; nt < 2; ++nt)
#pragma unroll
          for (int r = 0; r < 4; ++r) rs[nt][r] += __shfl_xor(rs[nt][r], d);
      if (li == 0) {
#pragma unroll
        for (int nt = 0; nt < 2; ++nt)
#pragma unroll
          for (int r = 0; r < 4; ++r)
            invr[w * 32 + nt * 16 + lk * 4 + r] = rs[nt][r];  // raw rowsum
      }
    }
    __syncthreads();
    if (tid < 128) {
      float csum = red[tid] + red[128 + tid] + red[256 + tid] + red[384 + tid];
      invc[tid] = 1.0f / sqrtf(csum);
      invr[tid] = 1.0f / sqrtf(invr[tid]);
    }
    __syncthreads();

    // normalize: A[n][m] = G * invc[n] * invr[m]  (ref quirk preserved)
    {
      float icf[2][4], irf[8];
#pragma unroll
      for (int nt = 0; nt < 2; ++nt)
#pragma unroll
        for (int r = 0; r < 4; ++r) icf[nt][r] = invc[w * 32 + nt * 16 + lk * 4 + r];
#pragma unroll
      for (int mt = 0; mt < 8; ++mt) irf[mt] = invr[mt * 16 + li];
#pragma unroll
      for (int nt = 0; nt < 2; ++nt)
#pragma unroll
        for (int mt = 0; mt < 8; ++mt)
#pragma unroll
          for (int r = 0; r < 4; ++r) acc[nt][mt][r] *= icf[nt][r] * irf[mt];
    }

    // s = x; 3 hops: w' = A w, s += w'
    float sv[2][4];
#pragma unroll
    for (int nt = 0; nt < 2; ++nt)
#pragma unroll
      for (int r = 0; r < 4; ++r) sv[nt][r] = wvb[0][w * 32 + nt * 16 + lk * 4 + r];
    int cur = 0;
    for (int h = 0; h < 3; ++h) {
      float wr[8];
#pragma unroll
      for (int mt = 0; mt < 8; ++mt) wr[mt] = wvb[cur][mt * 16 + li];
      float p[2][4];
#pragma unroll
      for (int nt = 0; nt < 2; ++nt)
#pragma unroll
        for (int r = 0; r < 4; ++r) {
          float s = 0.f;
#pragma unroll
          for (int mt = 0; mt < 8; ++mt) s += acc[nt][mt][r] * wr[mt];
          p[nt][r] = s;
        }
#pragma unroll
      for (int d = 1; d <= 8; d <<= 1)
#pragma unroll
        for (int nt = 0; nt < 2; ++nt)
#pragma unroll
          for (int r = 0; r < 4; ++r) p[nt][r] += __shfl_xor(p[nt][r], d);
#pragma unroll
      for (int nt = 0; nt < 2; ++nt)
#pragma unroll
        for (int r = 0; r < 4; ++r) sv[nt][r] += p[nt][r];
      if (li == 0) {
#pragma unroll
        for (int nt = 0; nt < 2; ++nt)
#pragma unroll
          for (int r = 0; r < 4; ++r)
            wvb[cur ^ 1][w * 32 + nt * 16 + lk * 4 + r] = p[nt][r];
      }
      __syncthreads();
      cur ^= 1;
    }
    if (li == 0) {
#pragma unroll
      for (int nt = 0; nt < 2; ++nt)
#pragma unroll
        for (int r = 0; r < 4; ++r)
          Xft[(b * 64 + f) * 128 + w * 32 + nt * 16 + lk * 4 + r] = sv[nt][r];
    }
    // next-tile writes to wvb[0]/Bs/red are ordered by the hop-loop barriers
  }
}

// k3: out[b][n][j] = sum_f Xft[b][f][n] * U[f][j]; grid (4 n-chunks, 32 b)
__global__ __launch_bounds__(256) void iag_k3_out(
    const float* __restrict__ Xft, const float* __restrict__ U,
    float* __restrict__ out) {
  __shared__ float Xf_s[64 * 36];                 // [f][nl], 144B rows
  __shared__ __align__(16) float U_s[64 * 64];
  int b = blockIdx.y, n0 = blockIdx.x * 32, tid = threadIdx.x;
  for (int c = tid; c < 512; c += 256) {
    int ff = c >> 3, s = c & 7;
    float4 v = *(const float4*)(Xft + (b * 64 + ff) * 128 + n0 + s * 4);
    *(float4*)(Xf_s + ff * 36 + s * 4) = v;
  }
  const float4* ug = (const float4*)U;
  float4* us = (float4*)U_s;
  for (int c = tid; c < 1024; c += 256) us[c] = ug[c];
  __syncthreads();

  int j0 = (tid & 15) * 4, nl0 = (tid >> 4) * 2;
  float a0[4] = {0.f, 0.f, 0.f, 0.f}, a1[4] = {0.f, 0.f, 0.f, 0.f};
  const float4* u4 = (const float4*)U_s;
#pragma unroll 4
  for (int ff = 0; ff < 64; ++ff) {
    float4 u = u4[ff * 16 + (j0 >> 2)];
    float xa = Xf_s[ff * 36 + nl0];
    float xb = Xf_s[ff * 36 + nl0 + 1];
    a0[0] += xa * u.x; a0[1] += xa * u.y; a0[2] += xa * u.z; a0[3] += xa * u.w;
    a1[0] += xb * u.x; a1[1] += xb * u.y; a1[2] += xb * u.z; a1[3] += xb * u.w;
  }
  *(float4*)(out + b * 8192 + (n0 + nl0) * 64 + j0) =
      make_float4(a0[0], a0[1], a0[2], a0[3]);
  *(float4*)(out + b * 8192 + (n0 + nl0 + 1) * 64 + j0) =
      make_float4(a1[0], a1[1], a1[2], a1[3]);
}

extern "C" void kernel_launch(void* const* d_in, const int* in_sizes, int n_in,
                              void* d_out, int out_size, void* d_ws, size_t ws_size,
                              hipStream_t stream) {
  const float* x  = (const float*)d_in[0];
  const float* P  = (const float*)d_in[1];
  const float* Bb = (const float*)d_in[2];
  const float* Q  = (const float*)d_in[3];
  const float* T  = (const float*)d_in[4];
  const float* U  = (const float*)d_in[5];
  char* wsb = (char*)d_ws;
  unsigned short* The = (unsigned short*)(wsb + WS_THE);
  unsigned short* Tle = (unsigned short*)(wsb + WS_TLE);
  unsigned short* OQh = (unsigned short*)(wsb + WS_OQH);
  unsigned short* OQl = (unsigned short*)(wsb + WS_OQL);
  float* Xft = (float*)(wsb + WS_XFT);
  float* xT  = (float*)(wsb + WS_XT);

  iag_kpre<<<256, 256, 0, stream>>>(T, x, P, Q, Bb, The, Tle, OQh, OQl, xT);
  iag_k2_graph<<<768, 256, 0, stream>>>(OQh, OQl, The, Tle, xT, Xft);
  iag_k3_out<<<dim3(4, 32), 256, 0, stream>>>(Xft, U, (float*)d_out);
}

// Round 11
// 107.713 us; speedup vs baseline: 1.1658x; 1.0193x over previous
//
#include <hip/hip_runtime.h>

// B=32, N=128, Fin=Fout=64, K_HOPS=4
// ws layout (BYTE offsets), total 5 MB:
//   The @ 0MB   : bf16-hi of T', FRAG-MAJOR per f: pos(m,k) =
//                 (k>>5)*4096 + (m>>4)*512 + (m&15)*32 + (k&31)   [shorts]
//   Tle @ 1MB   : bf16-lo, same layout
//   OQh @ 2MB   : bf16-hi of (Px+Bb)Q, row-major [b][n][k] = 512 KB
//   OQl @ 2.5MB : bf16-lo                                  = 512 KB
//   Xft @ 3MB   : f32 [b][f][n]                            = 1 MB
//   xT  @ 4MB   : f32 [b][f][n]                            = 1 MB

typedef __attribute__((ext_vector_type(8))) short short8v;
typedef __attribute__((ext_vector_type(4))) float f32x4;

#define WS_THE 0u
#define WS_TLE (1u << 20)
#define WS_OQH (2u << 20)
#define WS_OQL ((2u << 20) + (512u << 10))
#define WS_XFT (3u << 20)
#define WS_XT  (4u << 20)

__device__ __forceinline__ void split_bf16(float a, unsigned& hi, unsigned& lo) {
  unsigned ha = __float_as_uint(a) & 0xffff0000u;
  float d = a - __uint_as_float(ha);          // exact residual
  unsigned la = __float_as_uint(d) & 0xffff0000u;
  hi = ha; lo = la;                           // bf16 bits in TOP 16
}

// async global->LDS, 16B per lane; lds base must be wave-uniform
__device__ __forceinline__ void gload_lds16(const void* g, void* l) {
  __builtin_amdgcn_global_load_lds(
      (const __attribute__((address_space(1))) void*)g,
      (__attribute__((address_space(3))) void*)l, 16, 0, 0);
}

// kpre: blocks 0..63   -> T[k][m*64+f] -> The/Tle frag-major (transpose+split)
//       blocks 64..191 -> O = P x + Bb; OQh/OQl[b][n][k] = split((O Q)[n][k])
//       blocks 192..255-> x[b][n][f] -> xT[b][f][n] (LDS-tiled transpose)
__global__ __launch_bounds__(256) void iag_kpre(
    const float* __restrict__ T, const float* __restrict__ x,
    const float* __restrict__ P, const float* __restrict__ Q,
    const float* __restrict__ Bb,
    unsigned short* __restrict__ The, unsigned short* __restrict__ Tle,
    unsigned short* __restrict__ OQh, unsigned short* __restrict__ OQl,
    float* __restrict__ xT) {
  __shared__ __align__(16) char smem[73856];
  int bi = blockIdx.x, tid = threadIdx.x;

  if (bi < 64) {  // ---- T split-transpose: m-chunk of 2, all k, all f ----
    float* tile = (float*)smem;               // [64][129] f32
    int m0 = bi * 2;
    for (int idx = tid; idx < 8192; idx += 256) {
      int k = idx >> 7, j = idx & 127;        // j = ml*64 + f, coalesced read
      tile[k * 129 + j] = T[k * 8192 + m0 * 64 + j];
    }
    __syncthreads();
    int p = tid >> 1, kc = (tid & 1) * 32;
    int fj = p & 63, ml = p >> 6;
    int j = ml * 64 + fj;                     // bank (kk+j)%32: 2-way max
    unsigned hw[16], lw[16];
#pragma unroll
    for (int kk = 0; kk < 32; kk += 2) {
      float a0 = tile[(kc + kk) * 129 + j];
      float a1 = tile[(kc + kk + 1) * 129 + j];
      unsigned h0, l0, h1, l1;
      split_bf16(a0, h0, l0);
      split_bf16(a1, h1, l1);
      hw[kk >> 1] = (h0 >> 16) | h1;
      lw[kk >> 1] = (l0 >> 16) | l1;
    }
    int m = m0 + ml;
    // frag-major: (kc>>5)*4096 + (m>>4)*512 + (m&15)*32, 32 shorts contiguous
    int dofs = fj * 8192 + (kc >> 5) * 4096 + (m >> 4) * 512 + (m & 15) * 32;
    uint4* dh = (uint4*)(The + dofs);
    uint4* dl = (uint4*)(Tle + dofs);
#pragma unroll
    for (int i = 0; i < 4; ++i) {
      dh[i] = make_uint4(hw[4 * i], hw[4 * i + 1], hw[4 * i + 2], hw[4 * i + 3]);
      dl[i] = make_uint4(lw[4 * i], lw[4 * i + 1], lw[4 * i + 2], lw[4 * i + 3]);
    }
  } else if (bi < 192) {  // ---- OQ compute + split ----
    float* x_s   = (float*)smem;              // [128][64]
    float* ptile = x_s + 128 * 64;            // [32][129]
    float* Q_s   = ptile + 32 * 129;          // [64][64]
    float* OcT   = Q_s + 64 * 64;             // [64][32]
    int jb = bi - 64;
    int b = jb >> 2, r0 = (jb & 3) * 32;

    const float4* xg = (const float4*)(x + b * 8192);
    float4* xs4 = (float4*)x_s;
    for (int idx = tid; idx < 2048; idx += 256) xs4[idx] = xg[idx];
    for (int idx = tid; idx < 4096; idx += 256) {
      int nl = idx >> 7, m = idx & 127;
      ptile[nl * 129 + m] = P[(r0 + nl) * 128 + m];
    }
    const float4* qg = (const float4*)Q;
    float4* qs4 = (float4*)Q_s;
    for (int idx = tid; idx < 1024; idx += 256) qs4[idx] = qg[idx];
    __syncthreads();

    {  // Stage A: O[nl][k0..k0+7]
      int nl = tid & 31, k0 = (tid >> 5) * 8;
      float bias = Bb[r0 + nl];
      float a[8];
#pragma unroll
      for (int j = 0; j < 8; ++j) a[j] = bias;
#pragma unroll 4
      for (int m = 0; m < 128; ++m) {
        float p = ptile[nl * 129 + m];
        float4 x0 = xs4[m * 16 + (k0 >> 2)];
        float4 x1 = xs4[m * 16 + (k0 >> 2) + 1];
        a[0] += p * x0.x; a[1] += p * x0.y; a[2] += p * x0.z; a[3] += p * x0.w;
        a[4] += p * x1.x; a[5] += p * x1.y; a[6] += p * x1.z; a[7] += p * x1.w;
      }
#pragma unroll
      for (int j = 0; j < 8; ++j) OcT[(k0 + j) * 32 + nl] = a[j];
    }
    __syncthreads();
    {  // Stage B: row n = r0 + (tid>>3), cols j0..j0+7 of OQ; split+store
      int nl = tid >> 3, j0 = (tid & 7) * 8;
      float c[8];
#pragma unroll
      for (int i = 0; i < 8; ++i) c[i] = 0.f;
      const float4* q4 = (const float4*)Q_s;
#pragma unroll 4
      for (int k = 0; k < 64; ++k) {
        float o = OcT[k * 32 + nl];
        float4 q0 = q4[k * 16 + (j0 >> 2)];
        float4 q1 = q4[k * 16 + (j0 >> 2) + 1];
        c[0] += o * q0.x; c[1] += o * q0.y; c[2] += o * q0.z; c[3] += o * q0.w;
        c[4] += o * q1.x; c[5] += o * q1.y; c[6] += o * q1.z; c[7] += o * q1.w;
      }
      unsigned hw[4], lw[4];
#pragma unroll
      for (int j = 0; j < 8; j += 2) {
        unsigned h0, l0, h1, l1;
        split_bf16(c[j], h0, l0);
        split_bf16(c[j + 1], h1, l1);
        hw[j >> 1] = (h0 >> 16) | h1;
        lw[j >> 1] = (l0 >> 16) | l1;
      }
      int n = r0 + nl;
      *(uint4*)(OQh + b * 8192 + n * 64 + j0) = make_uint4(hw[0], hw[1], hw[2], hw[3]);
      *(uint4*)(OQl + b * 8192 + n * 64 + j0) = make_uint4(lw[0], lw[1], lw[2], lw[3]);
    }
  } else {  // ---- x -> xT LDS-tiled transpose ----
    float* tile = (float*)smem;               // [64][65] f32
    int j = bi - 192;
    int b = j >> 1, half = j & 1;
    const float* src = x + b * 8192 + half * 4096;
    float* dstbase = xT + b * 8192 + half * 64;
    for (int idx = tid; idx < 4096; idx += 256) {
      int c = idx & 63, r = idx >> 6;         // c = f (minor, coalesced read)
      tile[r * 65 + c] = src[idx];
    }
    __syncthreads();
    for (int idx = tid; idx < 4096; idx += 256) {
      int r = idx & 63, c = idx >> 6;         // r minor -> coalesced write
      dstbase[c * 128 + r] = tile[r * 65 + c];
    }
  }
}

// k2: grid 2048, one (f,b) tile per block (cross-block pipelining).
// G = OQ^T x Tf via split-bf16 MFMA (hh+hl+lh), relu, degree-normalize
// (ref quirk: colsum applied at n, rowsum at m), 3 matvec hops.
// B staged via async global_load_lds (frag-major global = identity copy).
__global__ __launch_bounds__(256, 3) void iag_k2_graph(
    const unsigned short* __restrict__ OQh, const unsigned short* __restrict__ OQl,
    const unsigned short* __restrict__ The, const unsigned short* __restrict__ Tle,
    const float* __restrict__ xT, float* __restrict__ Xft) {
  __shared__ unsigned short Bh_s[8192], Bl_s[8192];   // 16KB each, frag-major
  __shared__ float red[4 * 128];
  __shared__ float invc[128], invr[128];
  __shared__ float wvb[2][128];
  int tid = threadIdx.x;
  int lane = tid & 63, w = tid >> 6;
  int li = lane & 15, lk = lane >> 4;
  int t = blockIdx.x;
  int f = t & 63, b = t >> 6;

  // B-stage: async, identity copy (frag-major in global). Issued first.
  {
    const unsigned short* Bbh = The + f * 8192;
    const unsigned short* Bbl = Tle + f * 8192;
    int wb = w * 64;                           // wave-uniform chunk base
#pragma unroll
    for (int it = 0; it < 4; ++it) {
      int c = it * 256 + tid;                  // per-lane global chunk
      int cb = it * 256 + wb;                  // wave-uniform LDS chunk
      gload_lds16(Bbh + c * 8, Bh_s + cb * 8);
      gload_lds16(Bbl + c * 8, Bl_s + cb * 8);
    }
  }

  if (tid < 128) wvb[0][tid] = xT[(b * 64 + f) * 128 + tid];

  // A-frags direct-global (fly under the async stage)
  const unsigned short* Abh = OQh + b * 8192;
  const unsigned short* Abl = OQl + b * 8192;
  short8v ah[2][2], al[2][2];
#pragma unroll
  for (int nt = 0; nt < 2; ++nt)
#pragma unroll
    for (int kh = 0; kh < 2; ++kh) {
      int off = (w * 32 + nt * 16 + li) * 64 + kh * 32 + lk * 8;
      ah[nt][kh] = *(const short8v*)(Abh + off);
      al[nt][kh] = *(const short8v*)(Abl + off);
    }

  f32x4 acc[2][8];
#pragma unroll
  for (int nt = 0; nt < 2; ++nt)
#pragma unroll
    for (int mt = 0; mt < 8; ++mt) acc[nt][mt] = (f32x4){0.f, 0.f, 0.f, 0.f};

  __syncthreads();  // drains vmcnt -> stage complete

#pragma unroll
  for (int mt = 0; mt < 8; ++mt) {
    int base = mt * 512 + li * 32 + lk * 8;   // lane-contiguous 1KB per wave
    short8v bh0 = *(const short8v*)(Bh_s + base);
    short8v bh1 = *(const short8v*)(Bh_s + 4096 + base);
    short8v bl0 = *(const short8v*)(Bl_s + base);
    short8v bl1 = *(const short8v*)(Bl_s + 4096 + base);
#pragma unroll
    for (int nt = 0; nt < 2; ++nt) {
      f32x4 a = acc[nt][mt];
      a = __builtin_amdgcn_mfma_f32_16x16x32_bf16(ah[nt][0], bh0, a, 0, 0, 0);
      a = __builtin_amdgcn_mfma_f32_16x16x32_bf16(ah[nt][1], bh1, a, 0, 0, 0);
      a = __builtin_amdgcn_mfma_f32_16x16x32_bf16(ah[nt][0], bl0, a, 0, 0, 0);
      a = __builtin_amdgcn_mfma_f32_16x16x32_bf16(ah[nt][1], bl1, a, 0, 0, 0);
      a = __builtin_amdgcn_mfma_f32_16x16x32_bf16(al[nt][0], bh0, a, 0, 0, 0);
      a = __builtin_amdgcn_mfma_f32_16x16x32_bf16(al[nt][1], bh1, a, 0, 0, 0);
      acc[nt][mt] = a;
    }
  }

  // relu. Lane holds D[n][m]: n = 32w + nt*16 + lk*4 + r, m = mt*16 + li.
#pragma unroll
  for (int nt = 0; nt < 2; ++nt)
#pragma unroll
    for (int mt = 0; mt < 8; ++mt)
#pragma unroll
      for (int r = 0; r < 4; ++r) acc[nt][mt][r] = fmaxf(acc[nt][mt][r], 0.f);

  // colsum c[m] = sum_n G[n][m] (cross-wave via red)
#pragma unroll
  for (int mt = 0; mt < 8; ++mt) {
    float cs = 0.f;
#pragma unroll
    for (int nt = 0; nt < 2; ++nt)
#pragma unroll
      for (int r = 0; r < 4; ++r) cs += acc[nt][mt][r];
    cs += __shfl_xor(cs, 16);
    cs += __shfl_xor(cs, 32);
    if (lk == 0) red[w * 128 + mt * 16 + li] = cs;
  }
  // rowsum r[n] = sum_m G[n][m] (intra-wave butterfly over li)
  {
    float rs[2][4];
#pragma unroll
    for (int nt = 0; nt < 2; ++nt)
#pragma unroll
      for (int r = 0; r < 4; ++r) {
        float s = 0.f;
#pragma unroll
        for (int mt = 0; mt < 8; ++mt) s += acc[nt][mt][r];
        rs[nt][r] = s;
      }
#pragma unroll
    for (int d = 1; d <= 8; d <<= 1)
#pragma unroll
      for (int nt = 0; nt < 2; ++nt)
#pragma unroll
        for (int r = 0; r < 4; ++r) rs[nt][r] += __shfl_xor(rs[nt][r], d);
    if (li == 0) {
#pragma unroll
      for (int nt = 0; nt < 2; ++nt)
#pragma unroll
        for (int r = 0; r < 4; ++r)
          invr[w * 32 + nt * 16 + lk * 4 + r] = rs[nt][r];  // raw rowsum
    }
  }
  __syncthreads();
  if (tid < 128) {
    float csum = red[tid] + red[128 + tid] + red[256 + tid] + red[384 + tid];
    invc[tid] = 1.0f / sqrtf(csum);
    invr[tid] = 1.0f / sqrtf(invr[tid]);
  }
  __syncthreads();

  // normalize: A[n][m] = G * invc[n] * invr[m]  (ref quirk preserved)
  {
    float icf[2][4], irf[8];
#pragma unroll
    for (int nt = 0; nt < 2; ++nt)
#pragma unroll
      for (int r = 0; r < 4; ++r) icf[nt][r] = invc[w * 32 + nt * 16 + lk * 4 + r];
#pragma unroll
    for (int mt = 0; mt < 8; ++mt) irf[mt] = invr[mt * 16 + li];
#pragma unroll
    for (int nt = 0; nt < 2; ++nt)
#pragma unroll
      for (int mt = 0; mt < 8; ++mt)
#pragma unroll
        for (int r = 0; r < 4; ++r) acc[nt][mt][r] *= icf[nt][r] * irf[mt];
  }

  // s = x; 3 hops: w' = A w, s += w'
  float sv[2][4];
#pragma unroll
  for (int nt = 0; nt < 2; ++nt)
#pragma unroll
    for (int r = 0; r < 4; ++r) sv[nt][r] = wvb[0][w * 32 + nt * 16 + lk * 4 + r];
  int cur = 0;
  for (int h = 0; h < 3; ++h) {
    float wr[8];
#pragma unroll
    for (int mt = 0; mt < 8; ++mt) wr[mt] = wvb[cur][mt * 16 + li];
    float p[2][4];
#pragma unroll
    for (int nt = 0; nt < 2; ++nt)
#pragma unroll
      for (int r = 0; r < 4; ++r) {
        float s = 0.f;
#pragma unroll
        for (int mt = 0; mt < 8; ++mt) s += acc[nt][mt][r] * wr[mt];
        p[nt][r] = s;
      }
#pragma unroll
    for (int d = 1; d <= 8; d <<= 1)
#pragma unroll
      for (int nt = 0; nt < 2; ++nt)
#pragma unroll
        for (int r = 0; r < 4; ++r) p[nt][r] += __shfl_xor(p[nt][r], d);
#pragma unroll
    for (int nt = 0; nt < 2; ++nt)
#pragma unroll
      for (int r = 0; r < 4; ++r) sv[nt][r] += p[nt][r];
    if (li == 0) {
#pragma unroll
      for (int nt = 0; nt < 2; ++nt)
#pragma unroll
        for (int r = 0; r < 4; ++r)
          wvb[cur ^ 1][w * 32 + nt * 16 + lk * 4 + r] = p[nt][r];
    }
    __syncthreads();
    cur ^= 1;
  }
  if (li == 0) {
#pragma unroll
    for (int nt = 0; nt < 2; ++nt)
#pragma unroll
      for (int r = 0; r < 4; ++r)
        Xft[(b * 64 + f) * 128 + w * 32 + nt * 16 + lk * 4 + r] = sv[nt][r];
  }
}

// k3: out[b][n][j] = sum_f Xft[b][f][n] * U[f][j]; grid (4 n-chunks, 32 b)
__global__ __launch_bounds__(256) void iag_k3_out(
    const float* __restrict__ Xft, const float* __restrict__ U,
    float* __restrict__ out) {
  __shared__ float Xf_s[64 * 36];                 // [f][nl], 144B rows
  __shared__ __align__(16) float U_s[64 * 64];
  int b = blockIdx.y, n0 = blockIdx.x * 32, tid = threadIdx.x;
  for (int c = tid; c < 512; c += 256) {
    int ff = c >> 3, s = c & 7;
    float4 v = *(const float4*)(Xft + (b * 64 + ff) * 128 + n0 + s * 4);
    *(float4*)(Xf_s + ff * 36 + s * 4) = v;
  }
  const float4* ug = (const float4*)U;
  float4* us = (float4*)U_s;
  for (int c = tid; c < 1024; c += 256) us[c] = ug[c];
  __syncthreads();

  int j0 = (tid & 15) * 4, nl0 = (tid >> 4) * 2;
  float a0[4] = {0.f, 0.f, 0.f, 0.f}, a1[4] = {0.f, 0.f, 0.f, 0.f};
  const float4* u4 = (const float4*)U_s;
#pragma unroll 4
  for (int ff = 0; ff < 64; ++ff) {
    float4 u = u4[ff * 16 + (j0 >> 2)];
    float xa = Xf_s[ff * 36 + nl0];
    float xb = Xf_s[ff * 36 + nl0 + 1];
    a0[0] += xa * u.x; a0[1] += xa * u.y; a0[2] += xa * u.z; a0[3] += xa * u.w;
    a1[0] += xb * u.x; a1[1] += xb * u.y; a1[2] += xb * u.z; a1[3] += xb * u.w;
  }
  *(float4*)(out + b * 8192 + (n0 + nl0) * 64 + j0) =
      make_float4(a0[0], a0[1], a0[2], a0[3]);
  *(float4*)(out + b * 8192 + (n0 + nl0 + 1) * 64 + j0) =
      make_float4(a1[0], a1[1], a1[2], a1[3]);
}

extern "C" void kernel_launch(void* const* d_in, const int* in_sizes, int n_in,
                              void* d_out, int out_size, void* d_ws, size_t ws_size,
                              hipStream_t stream) {
  const float* x  = (const float*)d_in[0];
  const float* P  = (const float*)d_in[1];
  const float* Bb = (const float*)d_in[2];
  const float* Q  = (const float*)d_in[3];
  const float* T  = (const float*)d_in[4];
  const float* U  = (const float*)d_in[5];
  char* wsb = (char*)d_ws;
  unsigned short* The = (unsigned short*)(wsb + WS_THE);
  unsigned short* Tle = (unsigned short*)(wsb + WS_TLE);
  unsigned short* OQh = (unsigned short*)(wsb + WS_OQH);
  unsigned short* OQl = (unsigned short*)(wsb + WS_OQL);
  float* Xft = (float*)(wsb + WS_XFT);
  float* xT  = (float*)(wsb + WS_XT);

  iag_kpre<<<256, 256, 0, stream>>>(T, x, P, Q, Bb, The, Tle, OQh, OQl, xT);
  iag_k2_graph<<<2048, 256, 0, stream>>>(OQh, OQl, The, Tle, xT, Xft);
  iag_k3_out<<<dim3(4, 32), 256, 0, stream>>>(Xft, U, (float*)d_out);
}